// Round 7
// baseline (651.926 us; speedup 1.0000x reference)
//
#include <hip/hip_runtime.h>

// OverlapWindowMHA2d on MI355X (gfx950) — R8.
// prep_w ; prep_x (padded channel-last bf16) ; qkv_attn_g2 (512 thr, 8 waves
// 4Mx2N, global-xp B-frags, ONE barrier, 16 waves/CU) ; head_gemm (no LDS,
// no barriers, direct global reads).
// R8 theory: R7 still latency-bound at 2 waves/SIMD. Double concurrency via
// R3's 8-wave geometry WITHOUT the register cap that made R3 spill
// (launch_bounds(512,2) -> 256-reg budget, actual ~120 -> 4 waves/SIMD HW).
// head_gemm LDS staging was pure overhead (tile is L1-resident) -> drop it.
//
// FULL workspace layout (154,779,648 B; ws proven >= this in R7):
//   [0)           ocat bf16 [b][win 1024][n 16][c 384] = 100,663,296 B
//   [+100663296)  w1b bf16 576x192 (q rows pre-scaled)   (221184 B)
//   [+100884480)  w2b bf16 576x192 (q rows pre-scaled)   (221184 B)
//   [+101105664)  whb bf16 192x384                       (147456 B)
//   [+101253120)  xp  bf16 [8][132][132][192]         (53,526,528 B)
// FALLBACK (ws too small): R2-proven fused kernel, first four entries only.

typedef unsigned short u16;
using bf16x8 = __attribute__((ext_vector_type(8))) short;
using f32x4  = __attribute__((ext_vector_type(4))) float;
using u16x8  = __attribute__((ext_vector_type(8))) unsigned short;
using u16x4  = __attribute__((ext_vector_type(4))) unsigned short;

#define CIN   192
#define NW2   33
#define QSCALE 0.17677669529663687f

__device__ __forceinline__ u16 f2bf(float f) {
    unsigned int x; __builtin_memcpy(&x, &f, 4);
    return (u16)((x + 0x7FFFu + ((x >> 16) & 1u)) >> 16);
}
__device__ __forceinline__ int xcol(int c, int tok) {
    int blk = (c >> 3) ^ ((tok ^ (tok >> 4)) & 7);
    return blk * 8 + (c & 7);
}

// ---------------------------------------------------------------------------
// prep_w: weights -> bf16; q rows (co<192) pre-scaled by 1/sqrt(32).
// ---------------------------------------------------------------------------
__global__ void prep_w(const float* __restrict__ w1, const float* __restrict__ w2,
                       const float* __restrict__ wh,
                       u16* __restrict__ w1b, u16* __restrict__ w2b,
                       u16* __restrict__ whb) {
    int i = blockIdx.x * 256 + threadIdx.x;            // 294912 total
    if (i < 221184) {
        int j = (i < 110592) ? i : i - 110592;
        int co = j / 192;
        float v = ((i < 110592) ? w1 : w2)[j];
        if (co < 192) v *= QSCALE;
        ((i < 110592) ? w1b : w2b)[j] = f2bf(v);
    } else if (i < 294912) {
        int j = i - 221184;
        whb[j] = f2bf(wh[j]);
    }
}

// ---------------------------------------------------------------------------
// prep_x: x fp32 [b][c][128][128] -> xp bf16 [b][132][132][c] (pad=2 zeros).
// ---------------------------------------------------------------------------
__global__ __launch_bounds__(256, 2) void prep_x(const float* __restrict__ x,
                                                 u16* __restrict__ xp) {
    __shared__ __align__(16) u16 lt[128 * 200];        // 51.2 KB
    int bi = blockIdx.x;                               // 8 * 132 = 1056
    int b = bi / 132, hp = bi % 132;
    u16* orow = xp + ((size_t)(b * 132 + hp)) * 132 * 192;
    const int tid = threadIdx.x;

    if (hp >= 2 && hp < 130) {
        const int h = hp - 2;
        const float* xr = x + (size_t)b * 192 * 128 * 128 + (size_t)h * 128;
#pragma unroll
        for (int it = 0; it < 24; ++it) {
            int i = it * 256 + tid;                    // 6144 = c(192) x wq(32)
            int c = i >> 5, w0 = (i & 31) * 4;
            float4 v = *reinterpret_cast<const float4*>(&xr[(size_t)c * 16384 + w0]);
            lt[(w0 + 0) * 200 + xcol(c, w0 + 0)] = f2bf(v.x);
            lt[(w0 + 1) * 200 + xcol(c, w0 + 1)] = f2bf(v.y);
            lt[(w0 + 2) * 200 + xcol(c, w0 + 2)] = f2bf(v.z);
            lt[(w0 + 3) * 200 + xcol(c, w0 + 3)] = f2bf(v.w);
        }
        __syncthreads();
#pragma unroll
        for (int it = 0; it < 13; ++it) {              // 132 wp x 24 kc = 3168
            int i = it * 256 + tid;
            if (i < 3168) {
                int wp = i / 24, kc = i - wp * 24;
                u16x8 val = {};
                if (wp >= 2 && wp < 130) {
                    int w = wp - 2;
                    int blk = kc ^ ((w ^ (w >> 4)) & 7);
                    val = *reinterpret_cast<const u16x8*>(&lt[w * 200 + blk * 8]);
                }
                *reinterpret_cast<u16x8*>(&orow[(size_t)wp * 192 + kc * 8]) = val;
            }
        }
    } else {
#pragma unroll
        for (int it = 0; it < 13; ++it) {
            int i = it * 256 + tid;
            if (i < 3168) {
                u16x8 z = {};
                *reinterpret_cast<u16x8*>(&orow[(size_t)i * 8]) = z;
            }
        }
    }
}

// ---------------------------------------------------------------------------
// qkv_attn_g2: 512 threads = 8 waves (wm = wave>>1 co-strip of 144,
// wn = wave&1 token half of 32). B-frags direct from xp (global, L3-hot).
// acc[9][2] = 72 VGPR. ONE __syncthreads (restage -> attention).
// LDS 80896 B: qk[64][392] | vt[4][6][32][16] | pl[8][16][24].
// ---------------------------------------------------------------------------
__global__ __launch_bounds__(512, 2) void qkv_attn_g2(const u16* __restrict__ xp,
                                                      const u16* __restrict__ w1b,
                                                      const float* __restrict__ b1,
                                                      const u16* __restrict__ w2b,
                                                      const float* __restrict__ b2,
                                                      u16* __restrict__ ocat) {
    __shared__ __align__(16) char smem[80896];
    u16* qk = (u16*)smem;
    u16* vt = (u16*)(smem + 50176);
    u16* pl = (u16*)(smem + 74752);

    const int tid  = threadIdx.x;
    const int wave = tid >> 6, lane = tid & 63;
    const int lo16 = lane & 15, quad = lane >> 4;
    const int wm = wave >> 1, wn = wave & 1;

    const int swz = (blockIdx.x & 7) * 553 + (blockIdx.x >> 3);  // 4424 = 8*553
    const bool br0 = (swz < 2048);

    int b, wy, g;
    const u16* wb; const float* bias;
    if (br0) { b = swz >> 8; int rem = swz & 255; wy = rem >> 3; g = rem & 7;
               wb = w1b; bias = b1; }
    else     { int bi = swz - 2048; b = bi / 297; int rem = bi % 297;
               wy = rem / 9; g = rem % 9; wb = w2b; bias = b2; }

    // --- B-fragment pointers: tok = wn*32 + nt*16 + lo16, window = wn*2+nt ---
    const int d  = br0 ? 2 : 0;
    const int ty = lo16 >> 2, tx = lo16 & 3;
    const u16* bp[2];
#pragma unroll
    for (int nt = 0; nt < 2; ++nt) {
        int wx = g * 4 + wn * 2 + nt;
        if (!br0 && wx > 32) wx = 32;    // OOB window: valid memory, discarded
        int hp = d + wy * 4 + ty;
        int wp = d + wx * 4 + tx;
        bp[nt] = xp + (((size_t)b * 132 + hp) * 132 + wp) * 192 + quad * 8;
    }

    // --- QKV GEMM: co strip wm*144, tokens wn*32..+32, K=192 in 6 chunks ---
    f32x4 acc[9][2];
#pragma unroll
    for (int mt = 0; mt < 9; ++mt)
#pragma unroll
        for (int nt = 0; nt < 2; ++nt) acc[mt][nt] = f32x4{0.f, 0.f, 0.f, 0.f};

    const u16* wrow = wb + (size_t)(wm * 144 + lo16) * 192 + quad * 8;
#pragma unroll
    for (int s = 0; s < 6; ++s) {
        bf16x8 bfr[2];
        bfr[0] = *reinterpret_cast<const bf16x8*>(bp[0] + s * 32);
        bfr[1] = *reinterpret_cast<const bf16x8*>(bp[1] + s * 32);
#pragma unroll
        for (int mt = 0; mt < 9; ++mt) {
            bf16x8 afr = *reinterpret_cast<const bf16x8*>(&wrow[mt * 3072 + s * 32]);
            acc[mt][0] = __builtin_amdgcn_mfma_f32_16x16x32_bf16(afr, bfr[0], acc[mt][0], 0, 0, 0);
            acc[mt][1] = __builtin_amdgcn_mfma_f32_16x16x32_bf16(afr, bfr[1], acc[mt][1], 0, 0, 0);
        }
    }

    // --- restage: Q/K -> qk[tok][392] ; V -> vt transposed ---
#pragma unroll
    for (int mt = 0; mt < 9; ++mt) {
        int co0 = wm * 144 + mt * 16 + quad * 4;
        float4 bv = *reinterpret_cast<const float4*>(&bias[co0]);
        if (co0 < 192) { bv.x *= QSCALE; bv.y *= QSCALE; bv.z *= QSCALE; bv.w *= QSCALE; }
#pragma unroll
        for (int nt = 0; nt < 2; ++nt) {
            int tok = wn * 32 + nt * 16 + lo16;
            float v0 = acc[mt][nt][0] + bv.x, v1 = acc[mt][nt][1] + bv.y;
            float v2 = acc[mt][nt][2] + bv.z, v3 = acc[mt][nt][3] + bv.w;
            if (co0 < 384) {
                u16x4 pk = {f2bf(v0), f2bf(v1), f2bf(v2), f2bf(v3)};
                *reinterpret_cast<u16x4*>(&qk[tok * 392 + co0]) = pk;
            } else {
                int dh = co0 - 384;
                int head = dh >> 5, d0 = dh & 31;
                int win = tok >> 4, m = tok & 15;
                u16* vrow = &vt[((win * 6 + head) * 32 + d0) * 16 + m];
                vrow[0]  = f2bf(v0);
                vrow[16] = f2bf(v1);
                vrow[32] = f2bf(v2);
                vrow[48] = f2bf(v3);
            }
        }
    }
    __syncthreads();        // the ONLY barrier

    // --- attention: 2 waves per window (win = wave>>1), 3 heads each ---
    {
        const int win = wave >> 1;
        const int h0  = (wave & 1) * 3;
        const u16* qbase = qk + (size_t)(win * 16) * 392;
        const bf16x8 z8 = {};
        const f32x4 zc = {0.f, 0.f, 0.f, 0.f};
        bool dov; size_t dst = 0;
        if (br0) {
            int wg = wy * 32 + g * 4 + win;
            dst = (((size_t)(b * 1024 + wg)) * 16 + lo16) * 384;
            dov = true;
        } else {
            int wx = g * 4 + win;
            int h = wy * 4 + (lo16 >> 2) - 2;
            int w = wx * 4 + (lo16 & 3) - 2;
            dov = (wx < NW2) && (unsigned)h < 128u && (unsigned)w < 128u;
            if (dov) {
                int wg = (h >> 2) * 32 + (w >> 2);
                int nn = (h & 3) * 4 + (w & 3);
                dst = (((size_t)(b * 1024 + wg)) * 16 + nn) * 384 + 192;
            }
        }
#pragma unroll
        for (int hh = 0; hh < 3; ++hh) {
            const int head = h0 + hh;
            bf16x8 kfr = *reinterpret_cast<const bf16x8*>(
                &qbase[lo16 * 392 + 192 + head * 32 + quad * 8]);
            bf16x8 qfr = *reinterpret_cast<const bf16x8*>(
                &qbase[lo16 * 392 + head * 32 + quad * 8]);
            f32x4 st = __builtin_amdgcn_mfma_f32_16x16x32_bf16(kfr, qfr, zc, 0, 0, 0);
            float mx = fmaxf(fmaxf(st[0], st[1]), fmaxf(st[2], st[3]));
            mx = fmaxf(mx, __shfl_xor(mx, 16));
            mx = fmaxf(mx, __shfl_xor(mx, 32));
            float p0 = __expf(st[0] - mx), p1 = __expf(st[1] - mx);
            float p2 = __expf(st[2] - mx), p3 = __expf(st[3] - mx);
            float sum = p0 + p1 + p2 + p3;
            sum += __shfl_xor(sum, 16);
            sum += __shfl_xor(sum, 32);
            float inv = 1.0f / sum;
            u16x4 pk = {f2bf(p0), f2bf(p1), f2bf(p2), f2bf(p3)};
            *reinterpret_cast<u16x4*>(&pl[(wave * 16 + lo16) * 24 + quad * 4]) = pk;
            bf16x8 pf = (quad < 2)
                ? *reinterpret_cast<const bf16x8*>(&pl[(wave * 16 + lo16) * 24 + quad * 8]) : z8;
            const u16* vbase = &vt[(win * 6 + head) * 32 * 16];
#pragma unroll
            for (int half = 0; half < 2; ++half) {
                bf16x8 av = (quad < 2)
                    ? *reinterpret_cast<const bf16x8*>(&vbase[(half * 16 + lo16) * 16 + quad * 8]) : z8;
                f32x4 o = __builtin_amdgcn_mfma_f32_16x16x32_bf16(av, pf, zc, 0, 0, 0);
                if (dov) {
                    u16x4 ok = {f2bf(o[0] * inv), f2bf(o[1] * inv),
                                f2bf(o[2] * inv), f2bf(o[3] * inv)};
                    *reinterpret_cast<u16x4*>(&ocat[dst + head * 32 + half * 16 + quad * 4]) = ok;
                }
            }
        }
    }
}

// ---------------------------------------------------------------------------
// FALLBACK qkv_attn (R2-proven structure), used only if ws too small.
// ---------------------------------------------------------------------------
__global__ __launch_bounds__(256, 2) void qkv_attn_fb(const float* __restrict__ x,
                                                      const u16* __restrict__ w1b,
                                                      const float* __restrict__ b1,
                                                      const u16* __restrict__ w2b,
                                                      const float* __restrict__ b2,
                                                      u16* __restrict__ ocat) {
    __shared__ __align__(16) char smem[77824];
    u16* xl = (u16*)smem;
    u16* qk = (u16*)smem;
    u16* vt = (u16*)(smem + 50176);
    u16* pl = (u16*)(smem + 74752);

    const int tid  = threadIdx.x;
    const int wave = tid >> 6, lane = tid & 63;
    const int lo16 = lane & 15, quad = lane >> 4;

    const int swz = (blockIdx.x & 7) * 553 + (blockIdx.x >> 3);
    const bool br0 = (swz < 2048);

    int b, wy, g;
    const u16* wb; const float* bias;
    if (br0) { b = swz >> 8; int rem = swz & 255; wy = rem >> 3; g = rem & 7;
               wb = w1b; bias = b1; }
    else     { int bi = swz - 2048; b = bi / 297; int rem = bi % 297;
               wy = rem / 9; g = rem % 9; wb = w2b; bias = b2; }
    const int hbase = wy * 4, wbase = g * 16;

    if (br0) {
#pragma unroll
        for (int it = 0; it < 12; ++it) {
            int i = it * 256 + tid;
            int c = i >> 4, y = (i >> 2) & 3, xc = i & 3;
            const float4 v = *reinterpret_cast<const float4*>(
                &x[(((size_t)b * CIN + c) * 128 + hbase + y) * 128 + wbase + xc * 4]);
            int t0 = xc * 16 + y * 4;
            xl[(t0 + 0) * 200 + xcol(c, t0 + 0)] = f2bf(v.x);
            xl[(t0 + 1) * 200 + xcol(c, t0 + 1)] = f2bf(v.y);
            xl[(t0 + 2) * 200 + xcol(c, t0 + 2)] = f2bf(v.z);
            xl[(t0 + 3) * 200 + xcol(c, t0 + 3)] = f2bf(v.w);
        }
    } else {
#pragma unroll
        for (int it = 0; it < 12; ++it) {
            int i = it * 256 + tid;
            int c = i >> 4, y = (i >> 2) & 3, xc = i & 3;
            float e0, e1, e2, e3;
            int h = hbase + y - 2;
            int w0 = wbase + xc * 4 - 2;
            bool hok = (unsigned)h < 128u;
            const float* row = &x[(((size_t)b * CIN + c) * 128 + h) * 128];
            if (hok && w0 >= 0 && w0 + 3 < 128) {
                float2 p0 = *reinterpret_cast<const float2*>(&row[w0]);
                float2 p1 = *reinterpret_cast<const float2*>(&row[w0 + 2]);
                e0 = p0.x; e1 = p0.y; e2 = p1.x; e3 = p1.y;
            } else {
                e0 = (hok && w0 >= 0 && w0 < 128)         ? row[w0]     : 0.f;
                e1 = (hok && w0+1 >= 0 && w0+1 < 128)     ? row[w0 + 1] : 0.f;
                e2 = (hok && w0+2 >= 0 && w0+2 < 128)     ? row[w0 + 2] : 0.f;
                e3 = (hok && w0+3 >= 0 && w0+3 < 128)     ? row[w0 + 3] : 0.f;
            }
            int t0 = xc * 16 + y * 4;
            xl[(t0 + 0) * 200 + xcol(c, t0 + 0)] = f2bf(e0);
            xl[(t0 + 1) * 200 + xcol(c, t0 + 1)] = f2bf(e1);
            xl[(t0 + 2) * 200 + xcol(c, t0 + 2)] = f2bf(e2);
            xl[(t0 + 3) * 200 + xcol(c, t0 + 3)] = f2bf(e3);
        }
    }
    __syncthreads();

    f32x4 acc[9][4];
#pragma unroll
    for (int mt = 0; mt < 9; ++mt)
#pragma unroll
        for (int nt = 0; nt < 4; ++nt) acc[mt][nt] = f32x4{0.f, 0.f, 0.f, 0.f};

    const u16* wrow = wb + (size_t)(wave * 144 + lo16) * 192 + quad * 8;
#pragma unroll
    for (int s = 0; s < 6; ++s) {
        bf16x8 bfr[4];
#pragma unroll
        for (int nt = 0; nt < 4; ++nt) {
            int tok = nt * 16 + lo16;
            int kb = s * 4 + quad;
            bfr[nt] = *reinterpret_cast<const bf16x8*>(
                &xl[tok * 200 + (((kb ^ ((tok ^ (tok >> 4)) & 7)) << 3))]);
        }
#pragma unroll
        for (int mt = 0; mt < 9; ++mt) {
            bf16x8 afr = *reinterpret_cast<const bf16x8*>(&wrow[mt * 3072 + s * 32]);
#pragma unroll
            for (int nt = 0; nt < 4; ++nt)
                acc[mt][nt] = __builtin_amdgcn_mfma_f32_16x16x32_bf16(afr, bfr[nt], acc[mt][nt], 0, 0, 0);
        }
    }
    __syncthreads();

#pragma unroll
    for (int mt = 0; mt < 9; ++mt) {
        int co0 = wave * 144 + mt * 16 + quad * 4;
        float4 bv = *reinterpret_cast<const float4*>(&bias[co0]);
        if (co0 < 192) { bv.x *= QSCALE; bv.y *= QSCALE; bv.z *= QSCALE; bv.w *= QSCALE; }
#pragma unroll
        for (int nt = 0; nt < 4; ++nt) {
            int tok = nt * 16 + lo16;
            float v0 = acc[mt][nt][0] + bv.x, v1 = acc[mt][nt][1] + bv.y;
            float v2 = acc[mt][nt][2] + bv.z, v3 = acc[mt][nt][3] + bv.w;
            if (co0 < 384) {
                u16x4 pk = {f2bf(v0), f2bf(v1), f2bf(v2), f2bf(v3)};
                *reinterpret_cast<u16x4*>(&qk[tok * 392 + co0]) = pk;
            } else {
                int dh = co0 - 384;
                int head = dh >> 5, d0 = dh & 31;
                int win = tok >> 4, m = tok & 15;
                u16* vrow = &vt[((win * 6 + head) * 32 + d0) * 16 + m];
                vrow[0]  = f2bf(v0);
                vrow[16] = f2bf(v1);
                vrow[32] = f2bf(v2);
                vrow[48] = f2bf(v3);
            }
        }
    }
    __syncthreads();

    {
        const int win = wave;
        const u16* qbase = qk + (size_t)(win * 16) * 392;
        const bf16x8 z8 = {};
        const f32x4 zc = {0.f, 0.f, 0.f, 0.f};
        bool dov; size_t dst = 0;
        if (br0) {
            int wg = wy * 32 + g * 4 + win;
            dst = (((size_t)(b * 1024 + wg)) * 16 + lo16) * 384;
            dov = true;
        } else {
            int wx = g * 4 + win;
            int h = wy * 4 + (lo16 >> 2) - 2;
            int w = wx * 4 + (lo16 & 3) - 2;
            dov = (wx < NW2) && (unsigned)h < 128u && (unsigned)w < 128u;
            if (dov) {
                int wg = (h >> 2) * 32 + (w >> 2);
                int nn = (h & 3) * 4 + (w & 3);
                dst = (((size_t)(b * 1024 + wg)) * 16 + nn) * 384 + 192;
            }
        }
#pragma unroll
        for (int head = 0; head < 6; ++head) {
            bf16x8 kfr = *reinterpret_cast<const bf16x8*>(
                &qbase[lo16 * 392 + 192 + head * 32 + quad * 8]);
            bf16x8 qfr = *reinterpret_cast<const bf16x8*>(
                &qbase[lo16 * 392 + head * 32 + quad * 8]);
            f32x4 st = __builtin_amdgcn_mfma_f32_16x16x32_bf16(kfr, qfr, zc, 0, 0, 0);
            float mx = fmaxf(fmaxf(st[0], st[1]), fmaxf(st[2], st[3]));
            mx = fmaxf(mx, __shfl_xor(mx, 16));
            mx = fmaxf(mx, __shfl_xor(mx, 32));
            float p0 = __expf(st[0] - mx), p1 = __expf(st[1] - mx);
            float p2 = __expf(st[2] - mx), p3 = __expf(st[3] - mx);
            float sum = p0 + p1 + p2 + p3;
            sum += __shfl_xor(sum, 16);
            sum += __shfl_xor(sum, 32);
            float inv = 1.0f / sum;
            u16x4 pk = {f2bf(p0), f2bf(p1), f2bf(p2), f2bf(p3)};
            *reinterpret_cast<u16x4*>(&pl[(wave * 16 + lo16) * 24 + quad * 4]) = pk;
            bf16x8 pf = (quad < 2)
                ? *reinterpret_cast<const bf16x8*>(&pl[(wave * 16 + lo16) * 24 + quad * 8]) : z8;
            const u16* vbase = &vt[(win * 6 + head) * 32 * 16];
#pragma unroll
            for (int half = 0; half < 2; ++half) {
                bf16x8 av = (quad < 2)
                    ? *reinterpret_cast<const bf16x8*>(&vbase[(half * 16 + lo16) * 16 + quad * 8]) : z8;
                f32x4 o = __builtin_amdgcn_mfma_f32_16x16x32_bf16(av, pf, zc, 0, 0, 0);
                if (dov) {
                    u16x4 ok = {f2bf(o[0] * inv), f2bf(o[1] * inv),
                                f2bf(o[2] * inv), f2bf(o[3] * inv)};
                    *reinterpret_cast<u16x4*>(&ocat[dst + head * 32 + half * 16 + quad * 4]) = ok;
                }
            }
        }
    }
}

// ---------------------------------------------------------------------------
// head GEMM: out[b][co 192][h][w] = w_head(192x384) @ o_cat rows + bias.
// NO LDS, NO barriers: B-frags direct from ocat (L1-hot across waves, 16B
// loads), A direct from whb (L2). 32-token tiles, 4096 blocks.
// ---------------------------------------------------------------------------
__global__ __launch_bounds__(256, 4) void head_gemm(const u16* __restrict__ ocat,
                                                    const u16* __restrict__ whb,
                                                    const float* __restrict__ bh,
                                                    float* __restrict__ out) {
    const int tid = threadIdx.x;
    const int wave = tid >> 6, lane = tid & 63;
    const int lo16 = lane & 15, quad = lane >> 4;

    int bi = (blockIdx.x & 7) * 512 + (blockIdx.x >> 3);   // 4096 = 8*512
    int b = bi >> 9; int rem = bi & 511;
    int wy = rem >> 4, g = rem & 15;
    const int wg0 = wy * 32 + g * 2;
    const size_t gbase = ((size_t)(b * 1024 + wg0) * 16) * 384;

    const u16* brow0 = ocat + gbase + (size_t)lo16 * 384 + quad * 8;
    const u16* brow1 = brow0 + 16 * 384;
    const u16* arow  = whb + (size_t)(wave * 48 + lo16) * 384 + quad * 8;

    f32x4 acc[3][2];
#pragma unroll
    for (int mt = 0; mt < 3; ++mt)
#pragma unroll
        for (int nt = 0; nt < 2; ++nt) acc[mt][nt] = f32x4{0.f, 0.f, 0.f, 0.f};

#pragma unroll
    for (int s = 0; s < 12; ++s) {
        int k0 = s * 32;
        bf16x8 a0 = *reinterpret_cast<const bf16x8*>(arow + k0);
        bf16x8 a1 = *reinterpret_cast<const bf16x8*>(arow + 16 * 384 + k0);
        bf16x8 a2 = *reinterpret_cast<const bf16x8*>(arow + 32 * 384 + k0);
        bf16x8 b0 = *reinterpret_cast<const bf16x8*>(brow0 + k0);
        bf16x8 b1 = *reinterpret_cast<const bf16x8*>(brow1 + k0);
        acc[0][0] = __builtin_amdgcn_mfma_f32_16x16x32_bf16(a0, b0, acc[0][0], 0, 0, 0);
        acc[0][1] = __builtin_amdgcn_mfma_f32_16x16x32_bf16(a0, b1, acc[0][1], 0, 0, 0);
        acc[1][0] = __builtin_amdgcn_mfma_f32_16x16x32_bf16(a1, b0, acc[1][0], 0, 0, 0);
        acc[1][1] = __builtin_amdgcn_mfma_f32_16x16x32_bf16(a1, b1, acc[1][1], 0, 0, 0);
        acc[2][0] = __builtin_amdgcn_mfma_f32_16x16x32_bf16(a2, b0, acc[2][0], 0, 0, 0);
        acc[2][1] = __builtin_amdgcn_mfma_f32_16x16x32_bf16(a2, b1, acc[2][1], 0, 0, 0);
    }

    int h = wy * 4 + (lo16 >> 2);
    const int co_base = wave * 48;
#pragma unroll
    for (int mt = 0; mt < 3; ++mt) {
        int co0 = co_base + mt * 16 + quad * 4;
        const float4 bv = *reinterpret_cast<const float4*>(&bh[co0]);
#pragma unroll
        for (int r = 0; r < 4; ++r) {
            float bias = (r == 0) ? bv.x : (r == 1) ? bv.y : (r == 2) ? bv.z : bv.w;
#pragma unroll
            for (int nt = 0; nt < 2; ++nt) {
                int w = (g * 2 + nt) * 4 + (lo16 & 3);
                out[(((size_t)b * CIN + co0 + r) * 128 + h) * 128 + w] = acc[mt][nt][r] + bias;
            }
        }
    }
}

// ---------------------------------------------------------------------------
extern "C" void kernel_launch(void* const* d_in, const int* in_sizes, int n_in,
                              void* d_out, int out_size, void* d_ws, size_t ws_size,
                              hipStream_t stream) {
    const float* x  = (const float*)d_in[0];
    const float* w1 = (const float*)d_in[1];
    const float* b1 = (const float*)d_in[2];
    const float* w2 = (const float*)d_in[3];
    const float* b2 = (const float*)d_in[4];
    const float* wh = (const float*)d_in[5];
    const float* bh = (const float*)d_in[6];
    float* out = (float*)d_out;

    char* ws = (char*)d_ws;
    u16* ocat = (u16*)ws;
    u16* w1b  = (u16*)(ws + 100663296);
    u16* w2b  = (u16*)(ws + 100884480);
    u16* whb  = (u16*)(ws + 101105664);
    u16* xp   = (u16*)(ws + 101253120);

    const size_t need_full = 101253120u + 53526528u;   // 154,779,648 B

    prep_w<<<1152, 256, 0, stream>>>(w1, w2, wh, w1b, w2b, whb);
    if (ws_size >= need_full) {
        prep_x<<<1056, 256, 0, stream>>>(x, xp);
        qkv_attn_g2<<<4424, 512, 0, stream>>>(xp, w1b, b1, w2b, b2, ocat);
    } else {
        qkv_attn_fb<<<4424, 256, 0, stream>>>(x, w1b, b1, w2b, b2, ocat);
    }
    head_gemm<<<4096, 256, 0, stream>>>(ocat, whb, bh, out);
}

// Round 8
// 452.456 us; speedup vs baseline: 1.4409x; 1.4409x over previous
//
#include <hip/hip_runtime.h>

// OverlapWindowMHA2d on MI355X (gfx950) — R9.
// prep_w ; prep_x (padded channel-last bf16) ; qkv_attn (R7 structure + LDS
// x-tile staged from xp with vector bf16 copies) ; head_gemm (R5/R7 version).
//
// R9 theory: occupancy is register-locked at 2 waves/SIMD (proven R3/R4/R5/R8);
// the remaining lever is critical-path latency. R7's K-loop exposes ~24 L3-hot
// B-fragment loads per wave; stage the 24.6 KB x-tile into LDS once (6 b128
// reads + 6 b128 writes per thread, XOR-swizzled c8 blocks -> <=2-way bank
// conflicts), making the K-loop LDS-read + L2-A-stream only.
//
// FULL workspace layout (154,779,648 B; proven to fit in R7):
//   [0)           ocat bf16 [b][win 1024][n 16][c 384] = 100,663,296 B
//   [+100663296)  w1b bf16 576x192 (q rows pre-scaled)   (221184 B)
//   [+100884480)  w2b bf16 576x192 (q rows pre-scaled)   (221184 B)
//   [+101105664)  whb bf16 192x384                       (147456 B)
//   [+101253120)  xp  bf16 [8][132][132][192]         (53,526,528 B)
// FALLBACK (ws too small): R2-proven fused kernel, first four entries only.

typedef unsigned short u16;
using bf16x8 = __attribute__((ext_vector_type(8))) short;
using f32x4  = __attribute__((ext_vector_type(4))) float;
using u16x8  = __attribute__((ext_vector_type(8))) unsigned short;
using u16x4  = __attribute__((ext_vector_type(4))) unsigned short;

#define CIN   192
#define NW2   33
#define QSCALE 0.17677669529663687f

__device__ __forceinline__ u16 f2bf(float f) {
    unsigned int x; __builtin_memcpy(&x, &f, 4);
    return (u16)((x + 0x7FFFu + ((x >> 16) & 1u)) >> 16);
}
__device__ __forceinline__ int xcol(int c, int tok) {
    int blk = (c >> 3) ^ ((tok ^ (tok >> 4)) & 7);
    return blk * 8 + (c & 7);
}

// ---------------------------------------------------------------------------
// prep_w: weights -> bf16; q rows (co<192) pre-scaled by 1/sqrt(32).
// ---------------------------------------------------------------------------
__global__ void prep_w(const float* __restrict__ w1, const float* __restrict__ w2,
                       const float* __restrict__ wh,
                       u16* __restrict__ w1b, u16* __restrict__ w2b,
                       u16* __restrict__ whb) {
    int i = blockIdx.x * 256 + threadIdx.x;            // 294912 total
    if (i < 221184) {
        int j = (i < 110592) ? i : i - 110592;
        int co = j / 192;
        float v = ((i < 110592) ? w1 : w2)[j];
        if (co < 192) v *= QSCALE;
        ((i < 110592) ? w1b : w2b)[j] = f2bf(v);
    } else if (i < 294912) {
        int j = i - 221184;
        whb[j] = f2bf(wh[j]);
    }
}

// ---------------------------------------------------------------------------
// prep_x: x fp32 [b][c][128][128] -> xp bf16 [b][132][132][c] (pad=2 zeros).
// ---------------------------------------------------------------------------
__global__ __launch_bounds__(256, 2) void prep_x(const float* __restrict__ x,
                                                 u16* __restrict__ xp) {
    __shared__ __align__(16) u16 lt[128 * 200];        // 51.2 KB
    int bi = blockIdx.x;                               // 8 * 132 = 1056
    int b = bi / 132, hp = bi % 132;
    u16* orow = xp + ((size_t)(b * 132 + hp)) * 132 * 192;
    const int tid = threadIdx.x;

    if (hp >= 2 && hp < 130) {
        const int h = hp - 2;
        const float* xr = x + (size_t)b * 192 * 128 * 128 + (size_t)h * 128;
#pragma unroll
        for (int it = 0; it < 24; ++it) {
            int i = it * 256 + tid;                    // 6144 = c(192) x wq(32)
            int c = i >> 5, w0 = (i & 31) * 4;
            float4 v = *reinterpret_cast<const float4*>(&xr[(size_t)c * 16384 + w0]);
            lt[(w0 + 0) * 200 + xcol(c, w0 + 0)] = f2bf(v.x);
            lt[(w0 + 1) * 200 + xcol(c, w0 + 1)] = f2bf(v.y);
            lt[(w0 + 2) * 200 + xcol(c, w0 + 2)] = f2bf(v.z);
            lt[(w0 + 3) * 200 + xcol(c, w0 + 3)] = f2bf(v.w);
        }
        __syncthreads();
#pragma unroll
        for (int it = 0; it < 13; ++it) {              // 132 wp x 24 kc = 3168
            int i = it * 256 + tid;
            if (i < 3168) {
                int wp = i / 24, kc = i - wp * 24;
                u16x8 val = {};
                if (wp >= 2 && wp < 130) {
                    int w = wp - 2;
                    int blk = kc ^ ((w ^ (w >> 4)) & 7);
                    val = *reinterpret_cast<const u16x8*>(&lt[w * 200 + blk * 8]);
                }
                *reinterpret_cast<u16x8*>(&orow[(size_t)wp * 192 + kc * 8]) = val;
            }
        }
    } else {
#pragma unroll
        for (int it = 0; it < 13; ++it) {
            int i = it * 256 + tid;
            if (i < 3168) {
                u16x8 z = {};
                *reinterpret_cast<u16x8*>(&orow[(size_t)i * 8]) = z;
            }
        }
    }
}

// ---------------------------------------------------------------------------
// qkv_attn: 256 thr, 4 waves; wave = co-strip of 144; 4 windows per block.
// Phase 0: stage x-tile (64 tok x 192 ch bf16 = 24.6 KB) from xp into LDS
//   (vector b128 copies, c8 blocks XOR-swizzled by tok&7 -> <=2-way conflicts).
// Phase 1: QKV GEMM, B-frags from LDS, A-frags from global (L2-hot W).
// Phase 2: restage Q/K/V -> attention per wave=window, 6 heads.
// LDS 77824: xl[64][192] overlays qk[64][392]; vt; pl.  3 barriers.
// ---------------------------------------------------------------------------
__global__ __launch_bounds__(256, 2) void qkv_attn(const u16* __restrict__ xp,
                                                   const u16* __restrict__ w1b,
                                                   const float* __restrict__ b1,
                                                   const u16* __restrict__ w2b,
                                                   const float* __restrict__ b2,
                                                   u16* __restrict__ ocat) {
    __shared__ __align__(16) char smem[77824];
    u16* xl = (u16*)smem;                    // [64][192], swizzled c8 blocks
    u16* qk = (u16*)smem;                    // [64][392] (overlays xl)
    u16* vt = (u16*)(smem + 50176);          // [4][6][32][16]
    u16* pl = (u16*)(smem + 74752);          // [4][16][24]

    const int tid  = threadIdx.x;
    const int wave = tid >> 6, lane = tid & 63;
    const int lo16 = lane & 15, quad = lane >> 4;

    const int swz = (blockIdx.x & 7) * 553 + (blockIdx.x >> 3);  // 4424 = 8*553
    const bool br0 = (swz < 2048);

    int b, wy, g;
    const u16* wb; const float* bias;
    if (br0) { b = swz >> 8; int rem = swz & 255; wy = rem >> 3; g = rem & 7;
               wb = w1b; bias = b1; }
    else     { int bi = swz - 2048; b = bi / 297; int rem = bi % 297;
               wy = rem / 9; g = rem % 9; wb = w2b; bias = b2; }

    const int d = br0 ? 2 : 0;

    // --- Phase 0: stage x-tile. 1536 16B chunks; chunk idx -> (tok, c8l). ---
#pragma unroll
    for (int it = 0; it < 6; ++it) {
        int idx = it * 256 + tid;            // 0..1535
        int tok = idx / 24, c8l = idx - tok * 24;
        int nt = tok >> 4, l = tok & 15;
        int wx = g * 4 + nt;
        if (!br0 && wx > 32) wx = 32;        // OOB window: valid mem, discarded
        int hp = d + wy * 4 + (l >> 2);
        int wp = d + wx * 4 + (l & 3);
        int c8g = c8l ^ (tok & 7);           // bijective within each 8-group
        u16x8 v = *reinterpret_cast<const u16x8*>(
            &xp[(((size_t)b * 132 + hp) * 132 + wp) * 192 + c8g * 8]);
        *reinterpret_cast<u16x8*>(&xl[tok * 192 + c8l * 8]) = v;
    }
    __syncthreads();

    // --- Phase 1: QKV GEMM qkv[co 576][tok 64], K=192 in 6 chunks ---
    f32x4 acc[9][4];
#pragma unroll
    for (int mt = 0; mt < 9; ++mt)
#pragma unroll
        for (int nt = 0; nt < 4; ++nt) acc[mt][nt] = f32x4{0.f, 0.f, 0.f, 0.f};

    const u16* wrow = wb + (size_t)(wave * 144 + lo16) * 192 + quad * 8;
    const int sw = lo16 & 7;                 // tok&7 == lo16&7 for all nt
#pragma unroll
    for (int s = 0; s < 6; ++s) {
        const int kb = s * 4 + quad;
        bf16x8 bfr[4];
#pragma unroll
        for (int nt = 0; nt < 4; ++nt) {
            int tok = nt * 16 + lo16;
            bfr[nt] = *reinterpret_cast<const bf16x8*>(
                &xl[tok * 192 + ((kb ^ sw) << 3)]);
        }
#pragma unroll
        for (int mt = 0; mt < 9; ++mt) {
            bf16x8 afr = *reinterpret_cast<const bf16x8*>(&wrow[mt * 3072 + s * 32]);
#pragma unroll
            for (int nt = 0; nt < 4; ++nt)
                acc[mt][nt] = __builtin_amdgcn_mfma_f32_16x16x32_bf16(afr, bfr[nt], acc[mt][nt], 0, 0, 0);
        }
    }
    __syncthreads();     // all xl reads done before qk overwrites the region

    // --- Phase 2a: restage Q/K -> qk[tok][392] ; V -> vt transposed ---
#pragma unroll
    for (int mt = 0; mt < 9; ++mt) {
        int co0 = wave * 144 + mt * 16 + quad * 4;
        float4 bv = *reinterpret_cast<const float4*>(&bias[co0]);
        if (co0 < 192) { bv.x *= QSCALE; bv.y *= QSCALE; bv.z *= QSCALE; bv.w *= QSCALE; }
#pragma unroll
        for (int nt = 0; nt < 4; ++nt) {
            int tok = nt * 16 + lo16;
            float v0 = acc[mt][nt][0] + bv.x, v1 = acc[mt][nt][1] + bv.y;
            float v2 = acc[mt][nt][2] + bv.z, v3 = acc[mt][nt][3] + bv.w;
            if (co0 < 384) {
                u16x4 pk = {f2bf(v0), f2bf(v1), f2bf(v2), f2bf(v3)};
                *reinterpret_cast<u16x4*>(&qk[tok * 392 + co0]) = pk;
            } else {
                int dh = co0 - 384;
                int head = dh >> 5, d0 = dh & 31;
                int win = tok >> 4, m = tok & 15;
                u16* vrow = &vt[((win * 6 + head) * 32 + d0) * 16 + m];
                vrow[0]  = f2bf(v0);
                vrow[16] = f2bf(v1);
                vrow[32] = f2bf(v2);
                vrow[48] = f2bf(v3);
            }
        }
    }
    __syncthreads();

    // --- Phase 2b: attention, wave = window, 6 heads sequentially ---
    {
        const int win = wave;
        const u16* qbase = qk + (size_t)(win * 16) * 392;
        const bf16x8 z8 = {};
        const f32x4 zc = {0.f, 0.f, 0.f, 0.f};
        bool dov; size_t dst = 0;
        if (br0) {
            int wg = wy * 32 + g * 4 + win;
            dst = (((size_t)(b * 1024 + wg)) * 16 + lo16) * 384;
            dov = true;
        } else {
            int wx = g * 4 + win;
            int h = wy * 4 + (lo16 >> 2) - 2;
            int w = wx * 4 + (lo16 & 3) - 2;
            dov = (wx < NW2) && (unsigned)h < 128u && (unsigned)w < 128u;
            if (dov) {
                int wg = (h >> 2) * 32 + (w >> 2);
                int nn = (h & 3) * 4 + (w & 3);
                dst = (((size_t)(b * 1024 + wg)) * 16 + nn) * 384 + 192;
            }
        }
#pragma unroll
        for (int head = 0; head < 6; ++head) {
            bf16x8 kfr = *reinterpret_cast<const bf16x8*>(
                &qbase[lo16 * 392 + 192 + head * 32 + quad * 8]);
            bf16x8 qfr = *reinterpret_cast<const bf16x8*>(
                &qbase[lo16 * 392 + head * 32 + quad * 8]);
            f32x4 st = __builtin_amdgcn_mfma_f32_16x16x32_bf16(kfr, qfr, zc, 0, 0, 0);
            float mx = fmaxf(fmaxf(st[0], st[1]), fmaxf(st[2], st[3]));
            mx = fmaxf(mx, __shfl_xor(mx, 16));
            mx = fmaxf(mx, __shfl_xor(mx, 32));
            float p0 = __expf(st[0] - mx), p1 = __expf(st[1] - mx);
            float p2 = __expf(st[2] - mx), p3 = __expf(st[3] - mx);
            float sum = p0 + p1 + p2 + p3;
            sum += __shfl_xor(sum, 16);
            sum += __shfl_xor(sum, 32);
            float inv = 1.0f / sum;
            u16x4 pk = {f2bf(p0), f2bf(p1), f2bf(p2), f2bf(p3)};
            *reinterpret_cast<u16x4*>(&pl[(wave * 16 + lo16) * 24 + quad * 4]) = pk;
            bf16x8 pf = (quad < 2)
                ? *reinterpret_cast<const bf16x8*>(&pl[(wave * 16 + lo16) * 24 + quad * 8]) : z8;
            const u16* vbase = &vt[(win * 6 + head) * 32 * 16];
#pragma unroll
            for (int half = 0; half < 2; ++half) {
                bf16x8 av = (quad < 2)
                    ? *reinterpret_cast<const bf16x8*>(&vbase[(half * 16 + lo16) * 16 + quad * 8]) : z8;
                f32x4 o = __builtin_amdgcn_mfma_f32_16x16x32_bf16(av, pf, zc, 0, 0, 0);
                if (dov) {
                    u16x4 ok = {f2bf(o[0] * inv), f2bf(o[1] * inv),
                                f2bf(o[2] * inv), f2bf(o[3] * inv)};
                    *reinterpret_cast<u16x4*>(&ocat[dst + head * 32 + half * 16 + quad * 4]) = ok;
                }
            }
        }
    }
}

// ---------------------------------------------------------------------------
// FALLBACK qkv_attn (R2-proven structure), used only if ws too small.
// ---------------------------------------------------------------------------
__global__ __launch_bounds__(256, 2) void qkv_attn_fb(const float* __restrict__ x,
                                                      const u16* __restrict__ w1b,
                                                      const float* __restrict__ b1,
                                                      const u16* __restrict__ w2b,
                                                      const float* __restrict__ b2,
                                                      u16* __restrict__ ocat) {
    __shared__ __align__(16) char smem[77824];
    u16* xl = (u16*)smem;
    u16* qk = (u16*)smem;
    u16* vt = (u16*)(smem + 50176);
    u16* pl = (u16*)(smem + 74752);

    const int tid  = threadIdx.x;
    const int wave = tid >> 6, lane = tid & 63;
    const int lo16 = lane & 15, quad = lane >> 4;

    const int swz = (blockIdx.x & 7) * 553 + (blockIdx.x >> 3);
    const bool br0 = (swz < 2048);

    int b, wy, g;
    const u16* wb; const float* bias;
    if (br0) { b = swz >> 8; int rem = swz & 255; wy = rem >> 3; g = rem & 7;
               wb = w1b; bias = b1; }
    else     { int bi = swz - 2048; b = bi / 297; int rem = bi % 297;
               wy = rem / 9; g = rem % 9; wb = w2b; bias = b2; }
    const int hbase = wy * 4, wbase = g * 16;

    if (br0) {
#pragma unroll
        for (int it = 0; it < 12; ++it) {
            int i = it * 256 + tid;
            int c = i >> 4, y = (i >> 2) & 3, xc = i & 3;
            const float4 v = *reinterpret_cast<const float4*>(
                &x[(((size_t)b * CIN + c) * 128 + hbase + y) * 128 + wbase + xc * 4]);
            int t0 = xc * 16 + y * 4;
            xl[(t0 + 0) * 200 + xcol(c, t0 + 0)] = f2bf(v.x);
            xl[(t0 + 1) * 200 + xcol(c, t0 + 1)] = f2bf(v.y);
            xl[(t0 + 2) * 200 + xcol(c, t0 + 2)] = f2bf(v.z);
            xl[(t0 + 3) * 200 + xcol(c, t0 + 3)] = f2bf(v.w);
        }
    } else {
#pragma unroll
        for (int it = 0; it < 12; ++it) {
            int i = it * 256 + tid;
            int c = i >> 4, y = (i >> 2) & 3, xc = i & 3;
            float e0, e1, e2, e3;
            int h = hbase + y - 2;
            int w0 = wbase + xc * 4 - 2;
            bool hok = (unsigned)h < 128u;
            const float* row = &x[(((size_t)b * CIN + c) * 128 + h) * 128];
            if (hok && w0 >= 0 && w0 + 3 < 128) {
                float2 p0 = *reinterpret_cast<const float2*>(&row[w0]);
                float2 p1 = *reinterpret_cast<const float2*>(&row[w0 + 2]);
                e0 = p0.x; e1 = p0.y; e2 = p1.x; e3 = p1.y;
            } else {
                e0 = (hok && w0 >= 0 && w0 < 128)         ? row[w0]     : 0.f;
                e1 = (hok && w0+1 >= 0 && w0+1 < 128)     ? row[w0 + 1] : 0.f;
                e2 = (hok && w0+2 >= 0 && w0+2 < 128)     ? row[w0 + 2] : 0.f;
                e3 = (hok && w0+3 >= 0 && w0+3 < 128)     ? row[w0 + 3] : 0.f;
            }
            int t0 = xc * 16 + y * 4;
            xl[(t0 + 0) * 200 + xcol(c, t0 + 0)] = f2bf(e0);
            xl[(t0 + 1) * 200 + xcol(c, t0 + 1)] = f2bf(e1);
            xl[(t0 + 2) * 200 + xcol(c, t0 + 2)] = f2bf(e2);
            xl[(t0 + 3) * 200 + xcol(c, t0 + 3)] = f2bf(e3);
        }
    }
    __syncthreads();

    f32x4 acc[9][4];
#pragma unroll
    for (int mt = 0; mt < 9; ++mt)
#pragma unroll
        for (int nt = 0; nt < 4; ++nt) acc[mt][nt] = f32x4{0.f, 0.f, 0.f, 0.f};

    const u16* wrow = wb + (size_t)(wave * 144 + lo16) * 192 + quad * 8;
#pragma unroll
    for (int s = 0; s < 6; ++s) {
        bf16x8 bfr[4];
#pragma unroll
        for (int nt = 0; nt < 4; ++nt) {
            int tok = nt * 16 + lo16;
            int kb = s * 4 + quad;
            bfr[nt] = *reinterpret_cast<const bf16x8*>(
                &xl[tok * 200 + (((kb ^ ((tok ^ (tok >> 4)) & 7)) << 3))]);
        }
#pragma unroll
        for (int mt = 0; mt < 9; ++mt) {
            bf16x8 afr = *reinterpret_cast<const bf16x8*>(&wrow[mt * 3072 + s * 32]);
#pragma unroll
            for (int nt = 0; nt < 4; ++nt)
                acc[mt][nt] = __builtin_amdgcn_mfma_f32_16x16x32_bf16(afr, bfr[nt], acc[mt][nt], 0, 0, 0);
        }
    }
    __syncthreads();

#pragma unroll
    for (int mt = 0; mt < 9; ++mt) {
        int co0 = wave * 144 + mt * 16 + quad * 4;
        float4 bv = *reinterpret_cast<const float4*>(&bias[co0]);
        if (co0 < 192) { bv.x *= QSCALE; bv.y *= QSCALE; bv.z *= QSCALE; bv.w *= QSCALE; }
#pragma unroll
        for (int nt = 0; nt < 4; ++nt) {
            int tok = nt * 16 + lo16;
            float v0 = acc[mt][nt][0] + bv.x, v1 = acc[mt][nt][1] + bv.y;
            float v2 = acc[mt][nt][2] + bv.z, v3 = acc[mt][nt][3] + bv.w;
            if (co0 < 384) {
                u16x4 pk = {f2bf(v0), f2bf(v1), f2bf(v2), f2bf(v3)};
                *reinterpret_cast<u16x4*>(&qk[tok * 392 + co0]) = pk;
            } else {
                int dh = co0 - 384;
                int head = dh >> 5, d0 = dh & 31;
                int win = tok >> 4, m = tok & 15;
                u16* vrow = &vt[((win * 6 + head) * 32 + d0) * 16 + m];
                vrow[0]  = f2bf(v0);
                vrow[16] = f2bf(v1);
                vrow[32] = f2bf(v2);
                vrow[48] = f2bf(v3);
            }
        }
    }
    __syncthreads();

    {
        const int win = wave;
        const u16* qbase = qk + (size_t)(win * 16) * 392;
        const bf16x8 z8 = {};
        const f32x4 zc = {0.f, 0.f, 0.f, 0.f};
        bool dov; size_t dst = 0;
        if (br0) {
            int wg = wy * 32 + g * 4 + win;
            dst = (((size_t)(b * 1024 + wg)) * 16 + lo16) * 384;
            dov = true;
        } else {
            int wx = g * 4 + win;
            int h = wy * 4 + (lo16 >> 2) - 2;
            int w = wx * 4 + (lo16 & 3) - 2;
            dov = (wx < NW2) && (unsigned)h < 128u && (unsigned)w < 128u;
            if (dov) {
                int wg = (h >> 2) * 32 + (w >> 2);
                int nn = (h & 3) * 4 + (w & 3);
                dst = (((size_t)(b * 1024 + wg)) * 16 + nn) * 384 + 192;
            }
        }
#pragma unroll
        for (int head = 0; head < 6; ++head) {
            bf16x8 kfr = *reinterpret_cast<const bf16x8*>(
                &qbase[lo16 * 392 + 192 + head * 32 + quad * 8]);
            bf16x8 qfr = *reinterpret_cast<const bf16x8*>(
                &qbase[lo16 * 392 + head * 32 + quad * 8]);
            f32x4 st = __builtin_amdgcn_mfma_f32_16x16x32_bf16(kfr, qfr, zc, 0, 0, 0);
            float mx = fmaxf(fmaxf(st[0], st[1]), fmaxf(st[2], st[3]));
            mx = fmaxf(mx, __shfl_xor(mx, 16));
            mx = fmaxf(mx, __shfl_xor(mx, 32));
            float p0 = __expf(st[0] - mx), p1 = __expf(st[1] - mx);
            float p2 = __expf(st[2] - mx), p3 = __expf(st[3] - mx);
            float sum = p0 + p1 + p2 + p3;
            sum += __shfl_xor(sum, 16);
            sum += __shfl_xor(sum, 32);
            float inv = 1.0f / sum;
            u16x4 pk = {f2bf(p0), f2bf(p1), f2bf(p2), f2bf(p3)};
            *reinterpret_cast<u16x4*>(&pl[(wave * 16 + lo16) * 24 + quad * 4]) = pk;
            bf16x8 pf = (quad < 2)
                ? *reinterpret_cast<const bf16x8*>(&pl[(wave * 16 + lo16) * 24 + quad * 8]) : z8;
            const u16* vbase = &vt[(win * 6 + head) * 32 * 16];
#pragma unroll
            for (int half = 0; half < 2; ++half) {
                bf16x8 av = (quad < 2)
                    ? *reinterpret_cast<const bf16x8*>(&vbase[(half * 16 + lo16) * 16 + quad * 8]) : z8;
                f32x4 o = __builtin_amdgcn_mfma_f32_16x16x32_bf16(av, pf, zc, 0, 0, 0);
                if (dov) {
                    u16x4 ok = {f2bf(o[0] * inv), f2bf(o[1] * inv),
                                f2bf(o[2] * inv), f2bf(o[3] * inv)};
                    *reinterpret_cast<u16x4*>(&ocat[dst + head * 32 + half * 16 + quad * 4]) = ok;
                }
            }
        }
    }
}

// ---------------------------------------------------------------------------
// head GEMM: out[b][co 192][h][w] = w_head(192x384) @ o_cat rows + bias.
// 32-token tiles (bt 25 KB). Best-measured version (R5/R7).
// ---------------------------------------------------------------------------
__global__ __launch_bounds__(256, 6) void head_gemm(const u16* __restrict__ ocat,
                                                    const u16* __restrict__ whb,
                                                    const float* __restrict__ bh,
                                                    float* __restrict__ out) {
    __shared__ __align__(16) u16 bt[32 * 392];
    const int tid = threadIdx.x;
    const int wave = tid >> 6, lane = tid & 63;
    const int lo16 = lane & 15, quad = lane >> 4;

    int bi = (blockIdx.x & 7) * 512 + (blockIdx.x >> 3);   // 4096 = 8*512
    int b = bi >> 9; int rem = bi & 511;
    int wy = rem >> 4, g = rem & 15;
    const int wg0 = wy * 32 + g * 2;
    const size_t gbase = ((size_t)(b * 1024 + wg0) * 16) * 384;

#pragma unroll
    for (int it = 0; it < 6; ++it) {
        int i = it * 256 + tid;
        u16x8 v = *reinterpret_cast<const u16x8*>(&ocat[gbase + (size_t)i * 8]);
        int row = i / 48, kc = i - row * 48;
        *reinterpret_cast<u16x8*>(&bt[row * 392 + kc * 8]) = v;
    }
    __syncthreads();

    const int co_base = wave * 48;
    f32x4 acc[3][2];
#pragma unroll
    for (int mt = 0; mt < 3; ++mt)
#pragma unroll
        for (int nt = 0; nt < 2; ++nt) acc[mt][nt] = f32x4{0.f, 0.f, 0.f, 0.f};

#pragma unroll
    for (int s = 0; s < 12; ++s) {
        int k0 = s * 32;
        bf16x8 a[3], bb[2];
#pragma unroll
        for (int nt = 0; nt < 2; ++nt)
            bb[nt] = *reinterpret_cast<const bf16x8*>(&bt[(nt * 16 + lo16) * 392 + k0 + quad * 8]);
#pragma unroll
        for (int mt = 0; mt < 3; ++mt)
            a[mt] = *reinterpret_cast<const bf16x8*>(
                &whb[(size_t)(co_base + mt * 16 + lo16) * 384 + k0 + quad * 8]);
#pragma unroll
        for (int mt = 0; mt < 3; ++mt)
#pragma unroll
            for (int nt = 0; nt < 2; ++nt)
                acc[mt][nt] = __builtin_amdgcn_mfma_f32_16x16x32_bf16(a[mt], bb[nt], acc[mt][nt], 0, 0, 0);
    }

    int h = wy * 4 + (lo16 >> 2);
#pragma unroll
    for (int mt = 0; mt < 3; ++mt) {
        int co0 = co_base + mt * 16 + quad * 4;
        const float4 bv = *reinterpret_cast<const float4*>(&bh[co0]);
#pragma unroll
        for (int r = 0; r < 4; ++r) {
            float bias = (r == 0) ? bv.x : (r == 1) ? bv.y : (r == 2) ? bv.z : bv.w;
#pragma unroll
            for (int nt = 0; nt < 2; ++nt) {
                int w = (g * 2 + nt) * 4 + (lo16 & 3);
                out[(((size_t)b * CIN + co0 + r) * 128 + h) * 128 + w] = acc[mt][nt][r] + bias;
            }
        }
    }
}

// ---------------------------------------------------------------------------
extern "C" void kernel_launch(void* const* d_in, const int* in_sizes, int n_in,
                              void* d_out, int out_size, void* d_ws, size_t ws_size,
                              hipStream_t stream) {
    const float* x  = (const float*)d_in[0];
    const float* w1 = (const float*)d_in[1];
    const float* b1 = (const float*)d_in[2];
    const float* w2 = (const float*)d_in[3];
    const float* b2 = (const float*)d_in[4];
    const float* wh = (const float*)d_in[5];
    const float* bh = (const float*)d_in[6];
    float* out = (float*)d_out;

    char* ws = (char*)d_ws;
    u16* ocat = (u16*)ws;
    u16* w1b  = (u16*)(ws + 100663296);
    u16* w2b  = (u16*)(ws + 100884480);
    u16* whb  = (u16*)(ws + 101105664);
    u16* xp   = (u16*)(ws + 101253120);

    const size_t need_full = 101253120u + 53526528u;   // 154,779,648 B

    prep_w<<<1152, 256, 0, stream>>>(w1, w2, wh, w1b, w2b, whb);
    if (ws_size >= need_full) {
        prep_x<<<1056, 256, 0, stream>>>(x, xp);
        qkv_attn<<<4424, 256, 0, stream>>>(xp, w1b, b1, w2b, b2, ocat);
    } else {
        qkv_attn_fb<<<4424, 256, 0, stream>>>(x, w1b, b1, w2b, b2, ocat);
    }
    head_gemm<<<4096, 256, 0, stream>>>(ocat, whb, bh, out);
}